// Round 5
// baseline (199.649 us; speedup 1.0000x reference)
//
#include <hip/hip_runtime.h>
#include <cstdint>
#include <cstddef>

typedef unsigned short u16;
typedef unsigned int u32;
typedef unsigned long long u64;
typedef __bf16 bf16x8 __attribute__((ext_vector_type(8)));
typedef float f32x4 __attribute__((ext_vector_type(4)));

// float -> bf16 (RNE), raw bits
__device__ __forceinline__ u16 f2bf(float f) {
    unsigned int x = __builtin_bit_cast(unsigned int, f);
    x += 0x7FFFu + ((x >> 16) & 1u);
    return (u16)(x >> 16);
}

__device__ __forceinline__ bf16x8 ldfrag(const u16* p) {
    bf16x8 r;
    __builtin_memcpy(&r, (const u16*)__builtin_assume_aligned(p, 16), 16);
    return r;
}

// async global->LDS, 16B per lane; lds dest = wave-uniform base + lane*16
__device__ __forceinline__ void async16(u16* lds, const u16* g) {
    __builtin_amdgcn_global_load_lds(
        (const __attribute__((address_space(1))) void*)g,
        (__attribute__((address_space(3))) void*)lds,
        16, 0, 0);
}

// ------------------------------------------- prep: x->bf16  +  W transpose->bf16
__global__ __launch_bounds__(256) void prep(const float* __restrict__ x,
                                            u16* __restrict__ xb,
                                            const float* __restrict__ W,
                                            u16* __restrict__ Wt) {
    const int bx = blockIdx.x;
    if (bx < 6144) {               // cvt: 8192*768 floats, 4/thread
        const int i = (bx * 256 + threadIdx.x) * 4;
        float4 v = *reinterpret_cast<const float4*>(x + i);
        union { u16 e[4]; u64 u; } w;
        w.e[0] = f2bf(v.x); w.e[1] = f2bf(v.y); w.e[2] = f2bf(v.z); w.e[3] = f2bf(v.w);
        *reinterpret_cast<u64*>(xb + i) = w.u;
    } else {                       // W [768][2304] -> Wt [2304][768]
        const int R = 768, Ccols = 2304;
        __shared__ float tile[32][33];
        const int bb = bx - 6144;
        const int bxc = (bb % 72) * 32;   // col of W
        const int byr = (bb / 72) * 32;   // row of W
        const int tx = threadIdx.x & 31, ty = threadIdx.x >> 5;
        #pragma unroll
        for (int i = 0; i < 32; i += 8)
            tile[ty + i][tx] = W[(size_t)(byr + ty + i) * Ccols + bxc + tx];
        __syncthreads();
        #pragma unroll
        for (int i = 0; i < 32; i += 8)
            Wt[(size_t)(bxc + ty + i) * R + byr + tx] = f2bf(tile[tx][ty + i]);
    }
}

// ---------------------------------------------------------------- QKV GEMM
// [M=8192][N=2304] = A @ Wt^T + bias. BK=32 double-buffered, ONE barrier/iter.
// Q/K cols (<1536) -> qk[8192][1536] (Q pre-scaled 0.125);
// V cols (>=1536)  -> Vt[b*12+h][d][2048 tok] transposed, packed b64 stores.
__global__ __launch_bounds__(256) void qkv_gemm(const u16* __restrict__ A,
                                                const u16* __restrict__ Bt,   // [N][K]
                                                const float* __restrict__ bias,
                                                u16* __restrict__ qk,
                                                u16* __restrict__ Vt) {
    const int N = 2304, K = 768, QKW = 1536;
    __shared__ __align__(16) u16 sA[2][128 * 32];   // 2 x 8 KB
    __shared__ __align__(16) u16 sB[2][128 * 32];
    const int t = threadIdx.x;
    const int wave = t >> 6, lane = t & 63;
    const int quad = lane >> 4, l16 = lane & 15;
    const int wr = wave >> 1, wc = wave & 1;
    const int m0 = blockIdx.y * 128, n0 = blockIdx.x * 128;

    const int srow = wave * 32 + (lane >> 2);   // + j*16
    const int sseg = lane & 3;

    f32x4 acc[4][4] = {};

    auto stage = [&](int k0, int bi) {
        #pragma unroll
        for (int j = 0; j < 2; ++j) {
            const int row = srow + j * 16;
            async16(&sA[bi][0] + wave * 1024 + j * 512,
                    A + (size_t)(m0 + row) * K + k0 + sseg * 8);
            async16(&sB[bi][0] + wave * 1024 + j * 512,
                    Bt + (size_t)(n0 + row) * K + k0 + sseg * 8);
        }
    };

    stage(0, 0);
    __syncthreads();                    // drains prologue asyncs

    int buf = 0;
    for (int k0 = 0; k0 < K; k0 += 32) {
        if (k0 + 32 < K) stage(k0 + 32, buf ^ 1);   // into back buffer

        bf16x8 af[4], bfr[4];
        #pragma unroll
        for (int i = 0; i < 4; ++i)
            af[i] = ldfrag(&sA[buf][0] + (wr * 64 + i * 16 + l16) * 32 + quad * 8);
        #pragma unroll
        for (int j = 0; j < 4; ++j)
            bfr[j] = ldfrag(&sB[buf][0] + (wc * 64 + j * 16 + l16) * 32 + quad * 8);
        #pragma unroll
        for (int i = 0; i < 4; ++i)
            #pragma unroll
            for (int j = 0; j < 4; ++j)
                acc[i][j] = __builtin_amdgcn_mfma_f32_16x16x32_bf16(af[i], bfr[j], acc[i][j], 0, 0, 0);

        __syncthreads();                // reads done + this iter's asyncs drained
        buf ^= 1;
    }

    if (n0 < 1536) {
        // Q/K region: scalar stores, row stride 1536
        #pragma unroll
        for (int i = 0; i < 4; ++i)
            #pragma unroll
            for (int j = 0; j < 4; ++j) {
                const int col = n0 + wc * 64 + j * 16 + l16;
                const float bc = bias[col];
                const float scale = (col < 768) ? 0.125f : 1.0f;
                #pragma unroll
                for (int r = 0; r < 4; ++r) {
                    const int row = m0 + wr * 64 + i * 16 + quad * 4 + r;
                    qk[(size_t)row * QKW + col] = f2bf((acc[i][j][r] + bc) * scale);
                }
            }
    } else {
        // V region: lane holds 4 consecutive tokens of one d column -> b64 store
        const int h = ((n0 - 1536) >> 6) + wc;
        #pragma unroll
        for (int i = 0; i < 4; ++i) {
            const int grow = m0 + wr * 64 + i * 16 + quad * 4;
            const int b = grow >> 11, tok = grow & 2047;
            #pragma unroll
            for (int j = 0; j < 4; ++j) {
                const int d = j * 16 + l16;
                const float bc = bias[1536 + h * 64 + d];
                u32 lo = (u32)f2bf(acc[i][j][0] + bc) | ((u32)f2bf(acc[i][j][1] + bc) << 16);
                u32 hi = (u32)f2bf(acc[i][j][2] + bc) | ((u32)f2bf(acc[i][j][3] + bc) << 16);
                u64 pk = (u64)lo | ((u64)hi << 32);
                *reinterpret_cast<u64*>(Vt + ((size_t)((b * 12 + h) * 64 + d)) * 2048 + tok) = pk;
            }
        }
    }
}

// ---------------------------------------------------------------- attention
// Token-sliced S^T = K Q^T, Q in regs, P b64 round-trip, K and V^T both staged
// via async16 double buffers (V pre-transposed by gemm). 2 barriers/iter.
__global__ __launch_bounds__(256, 3) void attn_kernel(const u16* __restrict__ qk,
                                                      const u16* __restrict__ Vt,
                                                      float* __restrict__ out) {
    const int T = 2048, QKW = 1536, Cc = 768, Dh = 64;

    // balanced decode: co-resident blocks (stride 256) get qa = {x, 15-x, (x+8)&15}
    const int bid = blockIdx.x;
    const int rr = bid >> 8;
    const int ss = bid & 255;
    const int x = ss & 15;
    const int qa = (rr == 0) ? x : (rr == 1) ? (15 - x) : ((x + 8) & 15);
    const int qb = 31 - qa;
    const int hb = (ss >> 4) + (rr << 4);
    const int h = hb % 12, b = hb / 12;

    const int t = threadIdx.x;
    const int wave = t >> 6, lane = t & 63;
    const int quad = lane >> 4, l16 = lane & 15;

    __shared__ __align__(16) u16 sK[2][64 * 64];   // 16 KB, chunk ^= row&7
    __shared__ __align__(16) u16 sV[2][64 * 64];   // 16 KB, [d][tok], chunk ^= d&7
    __shared__ __align__(16) u16 sP[128 * 72];     // 18 KB

    const u16* qbase = qk + (size_t)b * T * QKW + (size_t)h * Dh;
    const u16* kbase = qbase + 768;
    const u16* vtb = Vt + (size_t)(b * 12 + h) * 64 * 2048;

    // Q B-frags in regs for whole kernel
    bf16x8 qf[8][2];
    #pragma unroll
    for (int cg = 0; cg < 8; ++cg) {
        const int qrow = ((cg < 4) ? qa * 64 : (qb * 64 - 64)) + cg * 16 + l16;
        const u16* p = qbase + (size_t)qrow * QKW + quad * 8;
        qf[cg][0] = ldfrag(p);
        qf[cg][1] = ldfrag(p + 32);
    }

    f32x4 oacc[2][4] = {};

    // staging map (both K and V^T tiles): row = j*32 + wave*8 + (lane>>3),
    // global chunk = (lane&7) ^ (row&7); LDS dest = uniform base + lane*16
    const int srow = wave * 8 + (lane >> 3);
    const int sch = (lane & 7) ^ ((lane >> 3) & 7);

    auto stageK = [&](int it, int bi) {
        #pragma unroll
        for (int j = 0; j < 2; ++j)
            async16(&sK[bi][0] + j * 2048 + wave * 512,
                    kbase + (size_t)(it * 64 + j * 32 + srow) * QKW + sch * 8);
    };
    auto stageV = [&](int it, int bi) {
        #pragma unroll
        for (int j = 0; j < 2; ++j)
            async16(&sV[bi][0] + j * 2048 + wave * 512,
                    vtb + (size_t)(j * 32 + srow) * 2048 + it * 64 + sch * 8);
    };

    stageK(0, 0);
    stageV(0, 0);
    __syncthreads();

    int buf = 0;
    for (int it = 0; it <= qb; ++it) {
        const bool more = (it < qb);
        if (more) stageK(it + 1, buf ^ 1);

        const bool act_a = (it <= qa);

        // ---- QK: A = wave's 16-token K slice, B = Q regs; relu(+diag mask) -> P
        bf16x8 kf0, kf1;
        {
            const u16* kr = &sK[buf][0] + (wave * 16 + l16) * 64;
            const int rsw = l16 & 7;
            kf0 = ldfrag(kr + ((quad ^ rsw) << 3));
            kf1 = ldfrag(kr + (((quad + 4) ^ rsw) << 3));
        }
        const int cg_lo = act_a ? 0 : 4;
        #pragma unroll
        for (int cg = 7; cg >= 0; --cg) {
            if (cg < cg_lo) break;
            f32x4 s = {};
            s = __builtin_amdgcn_mfma_f32_16x16x32_bf16(kf0, qf[cg][0], s, 0, 0, 0);
            s = __builtin_amdgcn_mfma_f32_16x16x32_bf16(kf1, qf[cg][1], s, 0, 0, 0);
            const bool diag = (cg < 4) ? (it == qa) : (it == qb);
            u32 bits[4];
            #pragma unroll
            for (int r = 0; r < 4; ++r) {
                float v = fmaxf(s[r], 0.0f);
                if (diag && (wave * 16 + quad * 4 + r > (cg & 3) * 16 + l16)) v = 0.0f;
                bits[r] = __builtin_bit_cast(u32, v);
            }
            u32 pk[2];
            pk[0] = (bits[1] & 0xFFFF0000u) | (bits[0] >> 16);
            pk[1] = (bits[3] & 0xFFFF0000u) | (bits[2] >> 16);
            __builtin_memcpy((u16*)__builtin_assume_aligned(
                                 sP + (cg * 16 + l16) * 72 + wave * 16 + quad * 4, 8),
                             pk, 8);
        }
        __syncthreads();   // P visible; drains K asyncs (full QK phase of slack)

        if (more) stageV(it + 1, buf ^ 1);   // drains at barrier2 (PV phase of slack)

        // ---- PV: O += P @ V^T
        #pragma unroll
        for (int kk = 0; kk < 2; ++kk) {
            bf16x8 ap1 = ldfrag(sP + (64 + wave * 16 + l16) * 72 + kk * 32 + quad * 8);
            bf16x8 ap0;
            if (act_a) ap0 = ldfrag(sP + (wave * 16 + l16) * 72 + kk * 32 + quad * 8);
            #pragma unroll
            for (int dt = 0; dt < 4; ++dt) {
                const int d = dt * 16 + l16;
                bf16x8 bv = ldfrag(&sV[buf][0] + d * 64 + (((kk * 4 + quad) ^ (l16 & 7)) << 3));
                oacc[1][dt] = __builtin_amdgcn_mfma_f32_16x16x32_bf16(ap1, bv, oacc[1][dt], 0, 0, 0);
                if (act_a)
                    oacc[0][dt] = __builtin_amdgcn_mfma_f32_16x16x32_bf16(ap0, bv, oacc[0][dt], 0, 0, 0);
            }
        }

        __syncthreads();   // V reads + P reads done; V asyncs drained
        buf ^= 1;
    }

    // ---- write O (fp32, C/D layout)
    #pragma unroll
    for (int g = 0; g < 2; ++g)
        #pragma unroll
        for (int dt = 0; dt < 4; ++dt)
            #pragma unroll
            for (int r = 0; r < 4; ++r) {
                const int tok = (g == 0 ? qa * 64 : qb * 64) + wave * 16 + quad * 4 + r;
                const int c = h * Dh + dt * 16 + l16;
                out[((size_t)b * T + tok) * Cc + c] = oacc[g][dt][r];
            }
}

// ---------------------------------------------------------------- launch
extern "C" void kernel_launch(void* const* d_in, const int* in_sizes, int n_in,
                              void* d_out, int out_size, void* d_ws, size_t ws_size,
                              hipStream_t stream) {
    const float* x    = (const float*)d_in[0];   // [4,2048,768]
    const float* W    = (const float*)d_in[1];   // [768,2304]
    const float* bias = (const float*)d_in[2];   // [2304]
    float* out = (float*)d_out;                  // [4,2048,768]

    char* ws = (char*)d_ws;
    const size_t xb_bytes = (size_t)8192 * 768 * 2;    // 12.6 MB
    const size_t wt_bytes = (size_t)2304 * 768 * 2;    //  3.5 MB
    const size_t qk_bytes = (size_t)8192 * 1536 * 2;   // 25.2 MB
    u16* xb = (u16*)ws;
    u16* Wt = (u16*)(ws + xb_bytes);
    u16* qk = (u16*)(ws + xb_bytes + wt_bytes);
    u16* Vt = (u16*)(ws + xb_bytes + wt_bytes + qk_bytes);   // 12.6 MB [48][64][2048]

    prep<<<6144 + 1728, 256, 0, stream>>>(x, xb, W, Wt);
    qkv_gemm<<<dim3(18, 64), 256, 0, stream>>>(xb, Wt, bias, qk, Vt);
    attn_kernel<<<768, 256, 0, stream>>>(qk, Vt, out);
}

// Round 6
// 191.933 us; speedup vs baseline: 1.0402x; 1.0402x over previous
//
#include <hip/hip_runtime.h>
#include <cstdint>
#include <cstddef>

typedef unsigned short u16;
typedef unsigned int u32;
typedef unsigned long long u64;
typedef __bf16 bf16x8 __attribute__((ext_vector_type(8)));
typedef float f32x4 __attribute__((ext_vector_type(4)));

// float -> bf16 (RNE), raw bits
__device__ __forceinline__ u16 f2bf(float f) {
    unsigned int x = __builtin_bit_cast(unsigned int, f);
    x += 0x7FFFu + ((x >> 16) & 1u);
    return (u16)(x >> 16);
}

__device__ __forceinline__ bf16x8 ldfrag(const u16* p) {
    bf16x8 r;
    __builtin_memcpy(&r, (const u16*)__builtin_assume_aligned(p, 16), 16);
    return r;
}

// async global->LDS, 16B per lane; lds dest = wave-uniform base + lane*16
__device__ __forceinline__ void async16(u16* lds, const u16* g) {
    __builtin_amdgcn_global_load_lds(
        (const __attribute__((address_space(1))) void*)g,
        (__attribute__((address_space(3))) void*)lds,
        16, 0, 0);
}

// ------------------------------------------- prep: x->bf16  +  W transpose->bf16
__global__ __launch_bounds__(256) void prep(const float* __restrict__ x,
                                            u16* __restrict__ xb,
                                            const float* __restrict__ W,
                                            u16* __restrict__ Wt) {
    const int bx = blockIdx.x;
    if (bx < 6144) {               // cvt: 8192*768 floats, 4/thread
        const int i = (bx * 256 + threadIdx.x) * 4;
        float4 v = *reinterpret_cast<const float4*>(x + i);
        union { u16 e[4]; u64 u; } w;
        w.e[0] = f2bf(v.x); w.e[1] = f2bf(v.y); w.e[2] = f2bf(v.z); w.e[3] = f2bf(v.w);
        *reinterpret_cast<u64*>(xb + i) = w.u;
    } else {                       // W [768][2304] -> Wt [2304][768]
        const int R = 768, Ccols = 2304;
        __shared__ float tile[32][33];
        const int bb = bx - 6144;
        const int bxc = (bb % 72) * 32;   // col of W
        const int byr = (bb / 72) * 32;   // row of W
        const int tx = threadIdx.x & 31, ty = threadIdx.x >> 5;
        #pragma unroll
        for (int i = 0; i < 32; i += 8)
            tile[ty + i][tx] = W[(size_t)(byr + ty + i) * Ccols + bxc + tx];
        __syncthreads();
        #pragma unroll
        for (int i = 0; i < 32; i += 8)
            Wt[(size_t)(bxc + ty + i) * R + byr + tx] = f2bf(tile[tx][ty + i]);
    }
}

// ---------------------------------------------------------------- QKV GEMM
// Bench-3 structure (measured fastest): BK=32, single LDS buffer, 2 barriers/iter,
// async16 staging. Q/K cols -> qk[8192][1536] (Q pre-scaled 0.125);
// V cols -> Vt[b*12+h][d][2048] transposed with packed b64 stores.
__global__ __launch_bounds__(256) void qkv_gemm(const u16* __restrict__ A,
                                                const u16* __restrict__ Bt,   // [N][K]
                                                const float* __restrict__ bias,
                                                u16* __restrict__ qk,
                                                u16* __restrict__ Vt) {
    const int N = 2304, K = 768, QKW = 1536;
    __shared__ __align__(16) u16 sA[128 * 32];   // 8 KB
    __shared__ __align__(16) u16 sB[128 * 32];   // 8 KB
    const int t = threadIdx.x;
    const int wave = t >> 6, lane = t & 63;
    const int quad = lane >> 4, l16 = lane & 15;
    const int wr = wave >> 1, wc = wave & 1;
    const int m0 = blockIdx.y * 128, n0 = blockIdx.x * 128;

    const int srow = wave * 32 + (lane >> 2);   // + j*16
    const int sseg = lane & 3;

    f32x4 acc[4][4] = {};

    for (int k0 = 0; k0 < K; k0 += 32) {
        __syncthreads();   // prev iter's ds_reads done before overwrite
        #pragma unroll
        for (int j = 0; j < 2; ++j) {
            const int row = srow + j * 16;
            async16(sA + wave * 1024 + j * 512,
                    A + (size_t)(m0 + row) * K + k0 + sseg * 8);
            async16(sB + wave * 1024 + j * 512,
                    Bt + (size_t)(n0 + row) * K + k0 + sseg * 8);
        }
        __syncthreads();   // asyncs drained -> LDS visible

        bf16x8 af[4], bfr[4];
        #pragma unroll
        for (int i = 0; i < 4; ++i)
            af[i] = ldfrag(sA + (wr * 64 + i * 16 + l16) * 32 + quad * 8);
        #pragma unroll
        for (int j = 0; j < 4; ++j)
            bfr[j] = ldfrag(sB + (wc * 64 + j * 16 + l16) * 32 + quad * 8);
        #pragma unroll
        for (int i = 0; i < 4; ++i)
            #pragma unroll
            for (int j = 0; j < 4; ++j)
                acc[i][j] = __builtin_amdgcn_mfma_f32_16x16x32_bf16(af[i], bfr[j], acc[i][j], 0, 0, 0);
    }

    if (n0 < 1536) {
        // Q/K region: scalar stores, row stride 1536
        #pragma unroll
        for (int i = 0; i < 4; ++i)
            #pragma unroll
            for (int j = 0; j < 4; ++j) {
                const int col = n0 + wc * 64 + j * 16 + l16;
                const float bc = bias[col];
                const float scale = (col < 768) ? 0.125f : 1.0f;
                #pragma unroll
                for (int r = 0; r < 4; ++r) {
                    const int row = m0 + wr * 64 + i * 16 + quad * 4 + r;
                    qk[(size_t)row * QKW + col] = f2bf((acc[i][j][r] + bc) * scale);
                }
            }
    } else {
        // V region: lane holds 4 consecutive tokens of one d column -> b64 store
        const int h = ((n0 - 1536) >> 6) + wc;
        #pragma unroll
        for (int i = 0; i < 4; ++i) {
            const int grow = m0 + wr * 64 + i * 16 + quad * 4;
            const int b = grow >> 11, tok = grow & 2047;
            #pragma unroll
            for (int j = 0; j < 4; ++j) {
                const int d = j * 16 + l16;
                const float bc = bias[1536 + h * 64 + d];
                u32 lo = (u32)f2bf(acc[i][j][0] + bc) | ((u32)f2bf(acc[i][j][1] + bc) << 16);
                u32 hi = (u32)f2bf(acc[i][j][2] + bc) | ((u32)f2bf(acc[i][j][3] + bc) << 16);
                u64 pk = (u64)lo | ((u64)hi << 32);
                *reinterpret_cast<u64*>(Vt + ((size_t)((b * 12 + h) * 64 + d)) * 2048 + tok) = pk;
            }
        }
    }
}

// ---------------------------------------------------------------- attention
// Token-sliced S^T = K Q^T, Q in regs, P b64 round-trip. K and V SINGLE-buffered
// (34 KB LDS -> 4 blocks/CU): stageK(it+1) after barrier1 (drains at barrier2),
// stageV(it+1) after barrier2 (drains at next barrier1) — full phase of slack each.
__global__ __launch_bounds__(256, 4) void attn_kernel(const u16* __restrict__ qk,
                                                      const u16* __restrict__ Vt,
                                                      float* __restrict__ out) {
    const int T = 2048, QKW = 1536, Cc = 768, Dh = 64;

    // balanced decode: co-resident blocks (stride 256) get qa = {x, 15-x, (x+8)&15}
    const int bid = blockIdx.x;
    const int rr = bid >> 8;
    const int ss = bid & 255;
    const int x = ss & 15;
    const int qa = (rr == 0) ? x : (rr == 1) ? (15 - x) : ((x + 8) & 15);
    const int qb = 31 - qa;
    const int hb = (ss >> 4) + (rr << 4);
    const int h = hb % 12, b = hb / 12;

    const int t = threadIdx.x;
    const int wave = t >> 6, lane = t & 63;
    const int quad = lane >> 4, l16 = lane & 15;

    __shared__ __align__(16) u16 sK[64 * 64];   // 8 KB, chunk ^= row&7
    __shared__ __align__(16) u16 sV[64 * 64];   // 8 KB, [d][tok], chunk ^= d&7
    __shared__ __align__(16) u16 sP[128 * 72];  // 18 KB

    const u16* qbase = qk + (size_t)b * T * QKW + (size_t)h * Dh;
    const u16* kbase = qbase + 768;
    const u16* vtb = Vt + (size_t)(b * 12 + h) * 64 * 2048;

    // Q B-frags in regs for whole kernel
    bf16x8 qf[8][2];
    #pragma unroll
    for (int cg = 0; cg < 8; ++cg) {
        const int qrow = ((cg < 4) ? qa * 64 : (qb * 64 - 64)) + cg * 16 + l16;
        const u16* p = qbase + (size_t)qrow * QKW + quad * 8;
        qf[cg][0] = ldfrag(p);
        qf[cg][1] = ldfrag(p + 32);
    }

    f32x4 oacc[2][4] = {};

    // staging map: row = j*32 + wave*8 + (lane>>3), global chunk = (lane&7)^(row&7)
    const int srow = wave * 8 + (lane >> 3);
    const int sch = (lane & 7) ^ ((lane >> 3) & 7);

    auto stageK = [&](int it) {
        #pragma unroll
        for (int j = 0; j < 2; ++j)
            async16(sK + j * 2048 + wave * 512,
                    kbase + (size_t)(it * 64 + j * 32 + srow) * QKW + sch * 8);
    };
    auto stageV = [&](int it) {
        #pragma unroll
        for (int j = 0; j < 2; ++j)
            async16(sV + j * 2048 + wave * 512,
                    vtb + (size_t)(j * 32 + srow) * 2048 + it * 64 + sch * 8);
    };

    stageK(0);
    stageV(0);
    __syncthreads();

    for (int it = 0; it <= qb; ++it) {
        const bool more = (it < qb);
        const bool act_a = (it <= qa);

        // ---- QK: A = wave's 16-token K slice, B = Q regs; relu(+diag mask) -> P
        bf16x8 kf0, kf1;
        {
            const u16* kr = sK + (wave * 16 + l16) * 64;
            const int rsw = l16 & 7;
            kf0 = ldfrag(kr + ((quad ^ rsw) << 3));
            kf1 = ldfrag(kr + (((quad + 4) ^ rsw) << 3));
        }
        const int cg_lo = act_a ? 0 : 4;
        #pragma unroll
        for (int cg = 7; cg >= 0; --cg) {
            if (cg < cg_lo) break;
            f32x4 s = {};
            s = __builtin_amdgcn_mfma_f32_16x16x32_bf16(kf0, qf[cg][0], s, 0, 0, 0);
            s = __builtin_amdgcn_mfma_f32_16x16x32_bf16(kf1, qf[cg][1], s, 0, 0, 0);
            const bool diag = (cg < 4) ? (it == qa) : (it == qb);
            u32 bits[4];
            #pragma unroll
            for (int r = 0; r < 4; ++r) {
                float v = fmaxf(s[r], 0.0f);
                if (diag && (wave * 16 + quad * 4 + r > (cg & 3) * 16 + l16)) v = 0.0f;
                bits[r] = __builtin_bit_cast(u32, v);
            }
            u32 pk[2];
            pk[0] = (bits[1] & 0xFFFF0000u) | (bits[0] >> 16);
            pk[1] = (bits[3] & 0xFFFF0000u) | (bits[2] >> 16);
            __builtin_memcpy((u16*)__builtin_assume_aligned(
                                 sP + (cg * 16 + l16) * 72 + wave * 16 + quad * 4, 8),
                             pk, 8);
        }
        __syncthreads();       // b1: P visible; sK reads done; V(it) asyncs drained

        if (more) stageK(it + 1);   // drains at b2; sK reads of it already done

        // ---- PV: O += P @ V^T
        #pragma unroll
        for (int kk = 0; kk < 2; ++kk) {
            bf16x8 ap1 = ldfrag(sP + (64 + wave * 16 + l16) * 72 + kk * 32 + quad * 8);
            bf16x8 ap0;
            if (act_a) ap0 = ldfrag(sP + (wave * 16 + l16) * 72 + kk * 32 + quad * 8);
            #pragma unroll
            for (int dt = 0; dt < 4; ++dt) {
                const int d = dt * 16 + l16;
                bf16x8 bv = ldfrag(sV + d * 64 + (((kk * 4 + quad) ^ (l16 & 7)) << 3));
                oacc[1][dt] = __builtin_amdgcn_mfma_f32_16x16x32_bf16(ap1, bv, oacc[1][dt], 0, 0, 0);
                if (act_a)
                    oacc[0][dt] = __builtin_amdgcn_mfma_f32_16x16x32_bf16(ap0, bv, oacc[0][dt], 0, 0, 0);
            }
        }
        __syncthreads();       // b2: sP/sV reads done; K(it+1) asyncs drained

        if (more) stageV(it + 1);   // drains at next b1; sV reads of it already done
    }

    // ---- write O (fp32, C/D layout)
    #pragma unroll
    for (int g = 0; g < 2; ++g)
        #pragma unroll
        for (int dt = 0; dt < 4; ++dt)
            #pragma unroll
            for (int r = 0; r < 4; ++r) {
                const int tok = (g == 0 ? qa * 64 : qb * 64) + wave * 16 + quad * 4 + r;
                const int c = h * Dh + dt * 16 + l16;
                out[((size_t)b * T + tok) * Cc + c] = oacc[g][dt][r];
            }
}

// ---------------------------------------------------------------- launch
extern "C" void kernel_launch(void* const* d_in, const int* in_sizes, int n_in,
                              void* d_out, int out_size, void* d_ws, size_t ws_size,
                              hipStream_t stream) {
    const float* x    = (const float*)d_in[0];   // [4,2048,768]
    const float* W    = (const float*)d_in[1];   // [768,2304]
    const float* bias = (const float*)d_in[2];   // [2304]
    float* out = (float*)d_out;                  // [4,2048,768]

    char* ws = (char*)d_ws;
    const size_t xb_bytes = (size_t)8192 * 768 * 2;    // 12.6 MB
    const size_t wt_bytes = (size_t)2304 * 768 * 2;    //  3.5 MB
    const size_t qk_bytes = (size_t)8192 * 1536 * 2;   // 25.2 MB
    u16* xb = (u16*)ws;
    u16* Wt = (u16*)(ws + xb_bytes);
    u16* qk = (u16*)(ws + xb_bytes + wt_bytes);
    u16* Vt = (u16*)(ws + xb_bytes + wt_bytes + qk_bytes);   // 12.6 MB [48][64][2048]

    prep<<<6144 + 1728, 256, 0, stream>>>(x, xb, W, Wt);
    qkv_gemm<<<dim3(18, 64), 256, 0, stream>>>(xb, Wt, bias, qk, Vt);
    attn_kernel<<<768, 256, 0, stream>>>(qk, Vt, out);
}